// Round 7
// baseline (137.171 us; speedup 1.0000x reference)
//
#include <hip/hip_runtime.h>

#define B_DIMC   128
#define S_DIMC   4096
#define N_TOK    (B_DIMC * S_DIMC)
#define CHUNK    512                 // tokens per block == scan chunk (8 waves)
#define NWAVE    8
#define N_CHUNK  (N_TOK / CHUNK)     // 1024
#define CPB      (S_DIMC / CHUNK)    // 8 chunks per batch

typedef __attribute__((ext_vector_type(8))) short  short8;   // 8 bf16 (4 VGPR) MFMA A/B frag
typedef __attribute__((ext_vector_type(4))) float  floatx4;  // MFMA C/D frag
typedef __attribute__((ext_vector_type(4))) int    intx4;

// packed f32->bf16 convert (RNE), lo=bf16(a) hi=bf16(b). No builtin on gfx950 -> inline asm.
__device__ __forceinline__ int cvtpk(float a, float b) {
    int r;
    asm("v_cvt_pk_bf16_f32 %0, %1, %2" : "=v"(r) : "v"(a), "v"(b));
    return r;
}

// tanh(x) = 1 - 2/(exp2(2*log2e*x)+1); med3 clamp keeps exp2 in range
__device__ __forceinline__ float fast_tanh(float x) {
    float e = __builtin_amdgcn_exp2f(2.885390082f * __builtin_amdgcn_fmed3f(x, -9.0f, 9.0f));
    return fmaf(-2.0f, __builtin_amdgcn_rcpf(e + 1.0f), 1.0f);
}
// tanh(a)*tanh(b) = (t-u)/(t+u),  t = ea*eb+1, u = ea+eb,  e* = exp2(2log2e*x)
__device__ __forceinline__ float gate2(float a, float b) {
    const float c = 2.885390082f;
    float ea = __builtin_amdgcn_exp2f(c * __builtin_amdgcn_fmed3f(a, -9.0f, 9.0f));
    float eb = __builtin_amdgcn_exp2f(c * __builtin_amdgcn_fmed3f(b, -9.0f, 9.0f));
    float t  = fmaf(ea, eb, 1.0f);
    float u  = ea + eb;
    return (t - u) * __builtin_amdgcn_rcpf(t + u);
}

// head weight element for column n, contraction index k (k = LOGICAL layer-1 output idx)
__device__ __forceinline__ float head_w(int n, int k,
                                        const float* Wal, const float* Wbe,
                                        const float* Wga, const float* Wc) {
    if (n == 0) return Wal[k];
    if (n == 1) return Wbe[k];
    if (n == 2) return Wga[k];
    if (n < 8)  return Wc[k * 5 + (n - 3)];
    return 0.0f;
}

// ---- Column-interleave permutation (gate-write pairing) ----
// Layer outputs store logical col c at PHYSICAL col p(c) = (c<16) ? 2c : 2(c-16)+1,
// so a thread's two gate outputs (logical n and n+16) land in ONE dword at int-idx n
// -> one cvtpk + one ds_write_b32 instead of two b16 writes. Consumers' B operands
// are staged with the inverse perm on their K index: c(p) = (p&1)*16 + (p>>1),
// i.e. physical pair kd holds logical rows {kd, kd+16}. The MFMA contraction is
// order-invariant, so results are bit-identical.

// LDS time-multiplex: B-staging area (phase 1) is dead once fragments are in
// registers; A-activation zones (phase 2) reuse the same bytes. Rows padded to
// 40 shorts (80 B). Union = exactly 40,960 B -> exactly 4 blocks/CU and 1024
// blocks = exactly 4 per CU. Wsum/Wpre are read strictly between barrier1 and
// barrier2 (the verified protocol); their bytes are only reused by A-zone
// traffic after barrier2, when dead.
union SMemU {
    struct {
        short W[4][32][40];    // [a0,b0,a1,b1][col n][k] bf16 (a1/b1 k-permuted)
        short Wh[16][40];      // head [col n][k] bf16 (k-permuted)
        float Bias[16];
        float Wsum[NWAVE];     // per-wave df2 scan totals
        float Wpre[NWAVE];     // per-wave partials of cross-chunk prefix
    } b;                       // total 11,648 B
    short A[NWAVE][64][40];    // per-wave activations (later fp32 head rows, stride 13)
};

// -------- single fused kernel: prefix + MFMA token-parallel MLP + scan --------
__global__ __launch_bounds__(512) void msc_kernel(
    const float* __restrict__ h_prev, const float* __restrict__ dx,
    const float* __restrict__ Wa0, const float* __restrict__ ba0,
    const float* __restrict__ Wb0, const float* __restrict__ bb0,
    const float* __restrict__ Wa1, const float* __restrict__ ba1,
    const float* __restrict__ Wb1, const float* __restrict__ bb1,
    const float* __restrict__ W_alpha, const float* __restrict__ b_alpha,
    const float* __restrict__ W_beta,  const float* __restrict__ b_beta,
    const float* __restrict__ W_gamma, const float* __restrict__ b_gamma,
    const float* __restrict__ W_c,     const float* __restrict__ b_c,
    const float* __restrict__ W_out,
    float* __restrict__ out)
{
    __shared__ __align__(16) SMemU sm;

    const int tid  = threadIdx.x;
    const int w    = tid >> 6;           // 0..7
    const int lane = tid & 63;
    const int n    = lane & 15;
    const int quad = lane >> 4;
    const int t    = blockIdx.x * CHUNK + tid;

    // ---- per-token global loads ----
    const float* hp = h_prev + (size_t)t * 5;
    const float* d  = dx     + (size_t)t * 6;
    const float hp0 = hp[0], hp1 = hp[1], hp2 = hp[2], hp3 = hp[3], hp4 = hp[4];
    const float df0 = d[0], df1 = d[1], df2 = d[2];

    // ---- cross-chunk prefix: sum dx[batch, 0:cib*CHUNK, 2], coalesced float4 ----
    const int batch = blockIdx.x >> 3;   // / CPB
    const int cib   = blockIdx.x & 7;    // % CPB
    const float* dxb = dx + (size_t)batch * S_DIMC * 6;
    const int nf4 = cib * 768;
    float ps = 0.0f;
    for (int j = tid; j < nf4; j += 512) {
        const float4 v = *(const float4*)(dxb + j * 4);
        const int r = j % 3;
        if (r == 0) ps += v.z;
        if (r == 2) ps += v.x;
    }
    ps += __shfl_xor(ps, 1, 64);
    ps += __shfl_xor(ps, 2, 64);
    ps += __shfl_xor(ps, 4, 64);
    ps += __shfl_xor(ps, 8, 64);
    ps += __shfl_xor(ps, 16, 64);
    ps += __shfl_xor(ps, 32, 64);
    if (lane == 0) sm.b.Wpre[w] = ps;

    // ---- per-lane fp32 epilogue weights (L1/L2-cached) ----
    float w5a[2], w5b[2], bA0[2], bB0[2], bA1[2], bB1[2];
    #pragma unroll
    for (int nt = 0; nt < 2; ++nt) {
        const int col = nt * 16 + n;
        w5a[nt] = Wa0[5 * 32 + col];  w5b[nt] = Wb0[5 * 32 + col];
        bA0[nt] = ba0[col];           bB0[nt] = bb0[col];
        bA1[nt] = ba1[col];           bB1[nt] = bb1[col];
    }

    // ---- wave-level inclusive scan of df2 ----
    float x = df2;
    #pragma unroll
    for (int off = 1; off < 64; off <<= 1) {
        float y = __shfl_up(x, off, 64);
        if (lane >= off) x += y;
    }
    if (lane == 63) sm.b.Wsum[w] = x;

    // ---- phase 1: cooperative B-operand build (single pass: 512 thr = 512 dwords) ----
    {
        const int col = tid >> 4, kd = tid & 15;
        // layer0 matrices: physical k = logical feature index (unpermuted)
        #pragma unroll
        for (int m = 0; m < 2; ++m) {
            const float* Wsrc = (m == 0) ? Wa0 : Wb0;
            const int k0 = kd * 2, k1 = k0 + 1;
            const float v0 = (k0 < 9 && k0 != 5) ? Wsrc[k0 * 32 + col] : 0.0f;
            const float v1 = (k1 < 9 && k1 != 5) ? Wsrc[k1 * 32 + col] : 0.0f;
            ((int*)&sm.b.W[m][col][0])[kd] = cvtpk(v0, v1);
        }
        // layer1 matrices: physical pair kd holds logical rows {kd, kd+16} (branchless)
        #pragma unroll
        for (int m = 2; m < 4; ++m) {
            const float* Wsrc = (m == 2) ? Wa1 : Wb1;
            ((int*)&sm.b.W[m][col][0])[kd] =
                cvtpk(Wsrc[kd * 32 + col], Wsrc[(kd + 16) * 32 + col]);
        }
    }
    if (tid < 256) {   // head B: 16 cols x 16 dwords, same k-perm as layer1 consumers
        const int hn = tid >> 4, kd = tid & 15;
        ((int*)&sm.b.Wh[hn][0])[kd] =
            cvtpk(head_w(hn, kd,      W_alpha, W_beta, W_gamma, W_c),
                  head_w(hn, kd + 16, W_alpha, W_beta, W_gamma, W_c));
    }
    if (tid < 16) {
        sm.b.Bias[tid] = (tid == 0) ? b_alpha[0] : (tid == 1) ? b_beta[0]
                       : (tid == 2) ? b_gamma[0] : (tid < 8) ? b_c[tid - 3] : 0.0f;
    }

    __syncthreads();   // barrier1: B staged + Wsum/Wpre visible

    // ---- B fragments to registers (reused across all 4 M-tiles) ----
    short8 Ba0f[2], Bb0f[2], Ba1f[2], Bb1f[2], Bhf;
    #pragma unroll
    for (int nt = 0; nt < 2; ++nt) {
        const int col = nt * 16 + n;
        Ba0f[nt] = *(const short8*)&sm.b.W[0][col][quad * 8];
        Bb0f[nt] = *(const short8*)&sm.b.W[1][col][quad * 8];
        Ba1f[nt] = *(const short8*)&sm.b.W[2][col][quad * 8];
        Bb1f[nt] = *(const short8*)&sm.b.W[3][col][quad * 8];
    }
    Bhf = *(const short8*)&sm.b.Wh[n][quad * 8];
    const float hbias = sm.b.Bias[n];

    // ---- temp_seq (fp32, stays out of bf16 path) ----
    float coff = dxb[5];
    #pragma unroll
    for (int ww = 0; ww < NWAVE; ++ww) coff += sm.b.Wpre[ww];
    float pre = coff;
    #pragma unroll
    for (int ww = 0; ww < NWAVE - 1; ++ww) if (w > ww) pre += sm.b.Wsum[ww];
    const float temp_t = pre + x;

    __syncthreads();   // barrier2: all waves done reading sm.b — safe to overwrite as sm.A

    // ---- phase 2: write layer0 A row: [h(5), 0(temp folded to C), dir(3), 0...] ----
    // fp32 temp goes in the row's pad dword 16.
    const float nrm = fmaxf(sqrtf(df0*df0 + df1*df1 + df2*df2), 1e-7f);
    const float inv = __builtin_amdgcn_rcpf(nrm);
    {
        int* arow = (int*)&sm.A[w][lane][0];
        intx4 v0 = { cvtpk(hp0, hp1), cvtpk(hp2, hp3),
                     cvtpk(hp4, 0.0f), cvtpk(df0*inv, df1*inv) };
        intx4 v1 = { cvtpk(df2*inv, 0.0f), 0, 0, 0 };
        intx4 z4 = { 0, 0, 0, 0 };
        *(intx4*)&arow[0]  = v0;
        *(intx4*)&arow[4]  = v1;
        *(intx4*)&arow[8]  = z4;
        *(intx4*)&arow[12] = z4;
        *(float*)&arow[16] = temp_t;
    }

    // ---- layer 0: C-init = bias + temp*W[5][n] (fp32), MFMA, gate, paired b32 write ----
    #pragma unroll
    for (int mt = 0; mt < 4; ++mt) {
        const short8 Af = *(const short8*)&sm.A[w][mt * 16 + n][quad * 8];
        const int rb = mt * 16 + quad * 4;
        floatx4 tv;
        #pragma unroll
        for (int r = 0; r < 4; ++r)
            tv[r] = *(const float*)&sm.A[w][rb + r][32];   // broadcast reads
        floatx4 g0, g1;
        {
            floatx4 Ca, Cb;
            #pragma unroll
            for (int r = 0; r < 4; ++r) {
                Ca[r] = fmaf(tv[r], w5a[0], bA0[0]);
                Cb[r] = fmaf(tv[r], w5b[0], bB0[0]);
            }
            Ca = __builtin_amdgcn_mfma_f32_16x16x32_bf16(Af, Ba0f[0], Ca, 0, 0, 0);
            Cb = __builtin_amdgcn_mfma_f32_16x16x32_bf16(Af, Bb0f[0], Cb, 0, 0, 0);
            #pragma unroll
            for (int r = 0; r < 4; ++r) g0[r] = gate2(Ca[r], Cb[r]);
        }
        {
            floatx4 Ca, Cb;
            #pragma unroll
            for (int r = 0; r < 4; ++r) {
                Ca[r] = fmaf(tv[r], w5a[1], bA0[1]);
                Cb[r] = fmaf(tv[r], w5b[1], bB0[1]);
            }
            Ca = __builtin_amdgcn_mfma_f32_16x16x32_bf16(Af, Ba0f[1], Ca, 0, 0, 0);
            Cb = __builtin_amdgcn_mfma_f32_16x16x32_bf16(Af, Bb0f[1], Cb, 0, 0, 0);
            #pragma unroll
            for (int r = 0; r < 4; ++r) g1[r] = gate2(Ca[r], Cb[r]);
        }
        #pragma unroll
        for (int r = 0; r < 4; ++r)
            ((int*)&sm.A[w][rb + r][0])[n] = cvtpk(g0[r], g1[r]);   // phys cols 2n,2n+1
    }

    // ---- layer 1 (B k-permuted to match the interleaved storage) ----
    #pragma unroll
    for (int mt = 0; mt < 4; ++mt) {
        const short8 Af = *(const short8*)&sm.A[w][mt * 16 + n][quad * 8];
        const int rb = mt * 16 + quad * 4;
        floatx4 g0, g1;
        {
            floatx4 Ca = { bA1[0], bA1[0], bA1[0], bA1[0] };
            floatx4 Cb = { bB1[0], bB1[0], bB1[0], bB1[0] };
            Ca = __builtin_amdgcn_mfma_f32_16x16x32_bf16(Af, Ba1f[0], Ca, 0, 0, 0);
            Cb = __builtin_amdgcn_mfma_f32_16x16x32_bf16(Af, Bb1f[0], Cb, 0, 0, 0);
            #pragma unroll
            for (int r = 0; r < 4; ++r) g0[r] = gate2(Ca[r], Cb[r]);
        }
        {
            floatx4 Ca = { bA1[1], bA1[1], bA1[1], bA1[1] };
            floatx4 Cb = { bB1[1], bB1[1], bB1[1], bB1[1] };
            Ca = __builtin_amdgcn_mfma_f32_16x16x32_bf16(Af, Ba1f[1], Ca, 0, 0, 0);
            Cb = __builtin_amdgcn_mfma_f32_16x16x32_bf16(Af, Bb1f[1], Cb, 0, 0, 0);
            #pragma unroll
            for (int r = 0; r < 4; ++r) g1[r] = gate2(Ca[r], Cb[r]);
        }
        #pragma unroll
        for (int r = 0; r < 4; ++r)
            ((int*)&sm.A[w][rb + r][0])[n] = cvtpk(g0[r], g1[r]);
    }

    // ---- heads: prefetch all A-frags, then MFMA + fp32 transpose via LDS ----
    // All traffic below is within this wave's private A zone; DS ops are in-order
    // per wave, so a compiler-only fence replaces a block barrier here.
    short8 Ah[4];
    #pragma unroll
    for (int mt = 0; mt < 4; ++mt)
        Ah[mt] = *(const short8*)&sm.A[w][mt * 16 + n][quad * 8];
    asm volatile("" ::: "memory");   // pin short-typed reads above before float stores below

    // fp32 transpose buffer: stride 13 dwords (odd -> lane*13 covers all 32 banks,
    // conflict-free b128 reads; was 12 -> 8-way). 64*13 = 832 <= 1280 dwords/zone.
    float* hc = (float*)&sm.A[w][0][0];
    #pragma unroll
    for (int mt = 0; mt < 4; ++mt) {
        floatx4 C = { hbias, hbias, hbias, hbias };
        C = __builtin_amdgcn_mfma_f32_16x16x32_bf16(Ah[mt], Bhf, C, 0, 0, 0);
        if (n < 8) {
            #pragma unroll
            for (int r = 0; r < 4; ++r)
                hc[(mt * 16 + quad * 4 + r) * 13 + n] = C[r];
        }
    }
    asm volatile("" ::: "memory");   // stores above complete (in-order DS) before reads below

    const floatx4 h0v = *(const floatx4*)&hc[lane * 13];      // pa, pb, pg, pc0
    const floatx4 h1v = *(const floatx4*)&hc[lane * 13 + 4];  // pc1..pc4

    // ---- per-token epilogue ----
    const float alpha = __expf(h0v[0]);
    const float beta  = __expf(h0v[1]);
    const float gamma = __expf(h0v[2]);
    const float z     = 1.0f - __expf(-(alpha * fabsf(df0) + beta * df1 + gamma * fabsf(df2)));
    const float omz   = 1.0f - z;

    const float c0 = fast_tanh(h0v[3]), c1 = fast_tanh(h1v[0]), c2 = fast_tanh(h1v[1]),
                c3 = fast_tanh(h1v[2]), c4 = fast_tanh(h1v[3]);

    const float hn0 = omz * hp0 + z * c0;
    const float hn1 = omz * hp1 + z * c1;
    const float hn2 = omz * hp2 + z * c2;
    const float hn3 = omz * hp3 + z * c3;
    const float hn4 = omz * hp4 + z * c4;

    float* out_h = out + (size_t)t * 5;
    out_h[0] = hn0; out_h[1] = hn1; out_h[2] = hn2; out_h[3] = hn3; out_h[4] = hn4;
    out[(size_t)N_TOK * 5 + t] =
        hn0 * W_out[0] + hn1 * W_out[1] + hn2 * W_out[2] + hn3 * W_out[3] + hn4 * W_out[4];
}

extern "C" void kernel_launch(void* const* d_in, const int* in_sizes, int n_in,
                              void* d_out, int out_size, void* d_ws, size_t ws_size,
                              hipStream_t stream) {
    const float* h_prev  = (const float*)d_in[0];
    const float* dx      = (const float*)d_in[1];
    const float* Wa0     = (const float*)d_in[2];
    const float* ba0     = (const float*)d_in[3];
    const float* Wb0     = (const float*)d_in[4];
    const float* bb0     = (const float*)d_in[5];
    const float* Wa1     = (const float*)d_in[6];
    const float* ba1     = (const float*)d_in[7];
    const float* Wb1     = (const float*)d_in[8];
    const float* bb1     = (const float*)d_in[9];
    const float* W_alpha = (const float*)d_in[10];
    const float* b_alpha = (const float*)d_in[11];
    const float* W_beta  = (const float*)d_in[12];
    const float* b_beta  = (const float*)d_in[13];
    const float* W_gamma = (const float*)d_in[14];
    const float* b_gamma = (const float*)d_in[15];
    const float* W_c     = (const float*)d_in[16];
    const float* b_c     = (const float*)d_in[17];
    const float* W_out   = (const float*)d_in[18];
    float* out = (float*)d_out;

    msc_kernel<<<N_CHUNK, CHUNK, 0, stream>>>(
        h_prev, dx,
        Wa0, ba0, Wb0, bb0, Wa1, ba1, Wb1, bb1,
        W_alpha, b_alpha, W_beta, b_beta, W_gamma, b_gamma,
        W_c, b_c, W_out, out);
}

// Round 8
// 129.850 us; speedup vs baseline: 1.0564x; 1.0564x over previous
//
#include <hip/hip_runtime.h>

#define B_DIMC   128
#define S_DIMC   4096
#define N_TOK    (B_DIMC * S_DIMC)
#define CHUNK    512                 // tokens per block == scan chunk (8 waves)
#define NWAVE    8
#define N_CHUNK  (N_TOK / CHUNK)     // 1024
#define CPB      (S_DIMC / CHUNK)    // 8 chunks per batch

typedef __attribute__((ext_vector_type(8))) short  short8;   // 8 bf16 (4 VGPR) MFMA A/B frag
typedef __attribute__((ext_vector_type(4))) float  floatx4;  // MFMA C/D frag
typedef __attribute__((ext_vector_type(4))) int    intx4;

// per-chunk sums of delta_x[...,2] — the round-0/1/2-verified cross-kernel
// mechanism (every block writes its own slot; consumer kernel is stream-ordered).
__device__ float g_chunksums[N_CHUNK];

// packed f32->bf16 convert (RNE), lo=bf16(a) hi=bf16(b). No builtin on gfx950 -> inline asm.
__device__ __forceinline__ int cvtpk(float a, float b) {
    int r;
    asm("v_cvt_pk_bf16_f32 %0, %1, %2" : "=v"(r) : "v"(a), "v"(b));
    return r;
}

// tanh(x) = 1 - 2/(exp2(2*log2e*x)+1); med3 clamp keeps exp2 in range
__device__ __forceinline__ float fast_tanh(float x) {
    float e = __builtin_amdgcn_exp2f(2.885390082f * __builtin_amdgcn_fmed3f(x, -9.0f, 9.0f));
    return fmaf(-2.0f, __builtin_amdgcn_rcpf(e + 1.0f), 1.0f);
}
// tanh(a)*tanh(b) = (t-u)/(t+u),  t = ea*eb+1, u = ea+eb,  e* = exp2(2log2e*x)
__device__ __forceinline__ float gate2(float a, float b) {
    const float c = 2.885390082f;
    float ea = __builtin_amdgcn_exp2f(c * __builtin_amdgcn_fmed3f(a, -9.0f, 9.0f));
    float eb = __builtin_amdgcn_exp2f(c * __builtin_amdgcn_fmed3f(b, -9.0f, 9.0f));
    float t  = fmaf(ea, eb, 1.0f);
    float u  = ea + eb;
    return (t - u) * __builtin_amdgcn_rcpf(t + u);
}

// head weight element for column n, contraction index k (k = LOGICAL layer-1 output idx)
__device__ __forceinline__ float head_w(int n, int k,
                                        const float* Wal, const float* Wbe,
                                        const float* Wga, const float* Wc) {
    if (n == 0) return Wal[k];
    if (n == 1) return Wbe[k];
    if (n == 2) return Wga[k];
    if (n < 8)  return Wc[k * 5 + (n - 3)];
    return 0.0f;
}

// -------- K1: per-chunk sum of delta_x[..., 2] --------
// Coalesced float4 sweep; chunk = 512 tokens = 3072 floats = 768 float4.
// Component o = 4j+c, keep o%6==2: j%3==0 -> v.z, j%3==2 -> v.x (verified pattern).
__global__ __launch_bounds__(512) void chunksum_kernel(const float* __restrict__ dx) {
    const int lane = threadIdx.x & 63;
    const int wid  = threadIdx.x >> 6;   // 0..7
    __shared__ float wsum[NWAVE];
    const float* base = dx + (size_t)blockIdx.x * (CHUNK * 6);
    float s = 0.0f;
    #pragma unroll
    for (int j = threadIdx.x; j < 768; j += 512) {
        const float4 v = *(const float4*)(base + j * 4);
        const int r = j % 3;
        if (r == 0) s += v.z;
        if (r == 2) s += v.x;
    }
    #pragma unroll
    for (int off = 32; off >= 1; off >>= 1) s += __shfl_down(s, off, 64);
    if (lane == 0) wsum[wid] = s;
    __syncthreads();
    if (threadIdx.x == 0) {
        float t = 0.0f;
        #pragma unroll
        for (int i = 0; i < NWAVE; ++i) t += wsum[i];
        g_chunksums[blockIdx.x] = t;
    }
}

// ---- Column-interleave permutation (gate-write pairing) ----
// Layer outputs store logical col c at PHYSICAL col p(c) = (c<16) ? 2c : 2(c-16)+1,
// so a thread's two gate outputs (logical n and n+16) land in ONE dword at int-idx n
// -> one cvtpk + one ds_write_b32 instead of two b16 writes. Consumers' B operands
// are staged with the inverse perm on their K index: physical pair kd holds logical
// rows {kd, kd+16}. The MFMA contraction is order-invariant -> bit-identical.

// LDS time-multiplex: B-staging area (phase 1) is dead once fragments are in
// registers; A-activation zones (phase 2) reuse the same bytes. Rows padded to
// 40 shorts (80 B). Union = exactly 40,960 B -> exactly 4 blocks/CU and 1024
// blocks = exactly 4 per CU (full grid co-resident, uniform work per block now
// that the prefix sweep is gone). Wsum is read strictly between barrier1 and
// barrier2 (the verified protocol).
union SMemU {
    struct {
        short W[4][32][40];    // [a0,b0,a1,b1][col n][k] bf16 (a1/b1 k-permuted)
        short Wh[16][40];      // head [col n][k] bf16 (k-permuted)
        float Bias[16];
        float Wsum[NWAVE];     // per-wave df2 scan totals
    } b;                       // 11,616 B
    short A[NWAVE][64][40];    // per-wave activations (later fp32 head rows, stride 13)
};

// -------- K2: MFMA token-parallel MLP with fused scan --------
__global__ __launch_bounds__(512) void msc_kernel(
    const float* __restrict__ h_prev, const float* __restrict__ dx,
    const float* __restrict__ Wa0, const float* __restrict__ ba0,
    const float* __restrict__ Wb0, const float* __restrict__ bb0,
    const float* __restrict__ Wa1, const float* __restrict__ ba1,
    const float* __restrict__ Wb1, const float* __restrict__ bb1,
    const float* __restrict__ W_alpha, const float* __restrict__ b_alpha,
    const float* __restrict__ W_beta,  const float* __restrict__ b_beta,
    const float* __restrict__ W_gamma, const float* __restrict__ b_gamma,
    const float* __restrict__ W_c,     const float* __restrict__ b_c,
    const float* __restrict__ W_out,
    float* __restrict__ out)
{
    __shared__ __align__(16) SMemU sm;

    const int tid  = threadIdx.x;
    const int w    = tid >> 6;           // 0..7
    const int lane = tid & 63;
    const int n    = lane & 15;
    const int quad = lane >> 4;
    const int t    = blockIdx.x * CHUNK + tid;

    // ---- per-token global loads ----
    const float* hp = h_prev + (size_t)t * 5;
    const float* d  = dx     + (size_t)t * 6;
    const float hp0 = hp[0], hp1 = hp[1], hp2 = hp[2], hp3 = hp[3], hp4 = hp[4];
    const float df0 = d[0], df1 = d[1], df2 = d[2];

    // ---- chunk offset: 1 load/lane + 8-lane butterfly + broadcast ----
    const int batch = blockIdx.x >> 3;   // / CPB
    const int cib   = blockIdx.x & 7;    // % CPB
    float cs = (lane < cib) ? g_chunksums[batch * CPB + lane] : 0.0f;
    cs += __shfl_xor(cs, 1, 64);
    cs += __shfl_xor(cs, 2, 64);
    cs += __shfl_xor(cs, 4, 64);
    const float csum = __builtin_bit_cast(float,
        __builtin_amdgcn_readfirstlane(__builtin_bit_cast(int, cs)));
    const float coff = dx[(size_t)batch * S_DIMC * 6 + 5] + csum;   // init_temp + prefix

    // ---- per-lane fp32 epilogue weights (L1/L2-cached) ----
    float w5a[2], w5b[2], bA0[2], bB0[2], bA1[2], bB1[2];
    #pragma unroll
    for (int nt = 0; nt < 2; ++nt) {
        const int col = nt * 16 + n;
        w5a[nt] = Wa0[5 * 32 + col];  w5b[nt] = Wb0[5 * 32 + col];
        bA0[nt] = ba0[col];           bB0[nt] = bb0[col];
        bA1[nt] = ba1[col];           bB1[nt] = bb1[col];
    }

    // ---- wave-level inclusive scan of df2 ----
    float x = df2;
    #pragma unroll
    for (int off = 1; off < 64; off <<= 1) {
        float y = __shfl_up(x, off, 64);
        if (lane >= off) x += y;
    }
    if (lane == 63) sm.b.Wsum[w] = x;

    // ---- phase 1: cooperative B-operand build (single pass: 512 thr = 512 dwords) ----
    {
        const int col = tid >> 4, kd = tid & 15;
        // layer0 matrices: physical k = logical feature index (unpermuted)
        #pragma unroll
        for (int m = 0; m < 2; ++m) {
            const float* Wsrc = (m == 0) ? Wa0 : Wb0;
            const int k0 = kd * 2, k1 = k0 + 1;
            const float v0 = (k0 < 9 && k0 != 5) ? Wsrc[k0 * 32 + col] : 0.0f;
            const float v1 = (k1 < 9 && k1 != 5) ? Wsrc[k1 * 32 + col] : 0.0f;
            ((int*)&sm.b.W[m][col][0])[kd] = cvtpk(v0, v1);
        }
        // layer1 matrices: physical pair kd holds logical rows {kd, kd+16} (branchless)
        #pragma unroll
        for (int m = 2; m < 4; ++m) {
            const float* Wsrc = (m == 2) ? Wa1 : Wb1;
            ((int*)&sm.b.W[m][col][0])[kd] =
                cvtpk(Wsrc[kd * 32 + col], Wsrc[(kd + 16) * 32 + col]);
        }
    }
    if (tid < 256) {   // head B: 16 cols x 16 dwords, same k-perm as layer1 consumers
        const int hn = tid >> 4, kd = tid & 15;
        ((int*)&sm.b.Wh[hn][0])[kd] =
            cvtpk(head_w(hn, kd,      W_alpha, W_beta, W_gamma, W_c),
                  head_w(hn, kd + 16, W_alpha, W_beta, W_gamma, W_c));
    }
    if (tid < 16) {
        sm.b.Bias[tid] = (tid == 0) ? b_alpha[0] : (tid == 1) ? b_beta[0]
                       : (tid == 2) ? b_gamma[0] : (tid < 8) ? b_c[tid - 3] : 0.0f;
    }

    __syncthreads();   // barrier1: B staged + Wsum visible

    // ---- B fragments to registers (reused across all 4 M-tiles) ----
    short8 Ba0f[2], Bb0f[2], Ba1f[2], Bb1f[2], Bhf;
    #pragma unroll
    for (int nt = 0; nt < 2; ++nt) {
        const int col = nt * 16 + n;
        Ba0f[nt] = *(const short8*)&sm.b.W[0][col][quad * 8];
        Bb0f[nt] = *(const short8*)&sm.b.W[1][col][quad * 8];
        Ba1f[nt] = *(const short8*)&sm.b.W[2][col][quad * 8];
        Bb1f[nt] = *(const short8*)&sm.b.W[3][col][quad * 8];
    }
    Bhf = *(const short8*)&sm.b.Wh[n][quad * 8];
    const float hbias = sm.b.Bias[n];

    // ---- temp_seq (fp32, stays out of bf16 path) ----
    float pre = coff;
    #pragma unroll
    for (int ww = 0; ww < NWAVE - 1; ++ww) if (w > ww) pre += sm.b.Wsum[ww];
    const float temp_t = pre + x;

    __syncthreads();   // barrier2: all waves done reading sm.b — safe to overwrite as sm.A

    // ---- phase 2: write layer0 A row: [h(5), 0(temp folded to C), dir(3), 0...] ----
    // fp32 temp goes in the row's pad dword 16.
    const float nrm = fmaxf(sqrtf(df0*df0 + df1*df1 + df2*df2), 1e-7f);
    const float inv = __builtin_amdgcn_rcpf(nrm);
    {
        int* arow = (int*)&sm.A[w][lane][0];
        intx4 v0 = { cvtpk(hp0, hp1), cvtpk(hp2, hp3),
                     cvtpk(hp4, 0.0f), cvtpk(df0*inv, df1*inv) };
        intx4 v1 = { cvtpk(df2*inv, 0.0f), 0, 0, 0 };
        intx4 z4 = { 0, 0, 0, 0 };
        *(intx4*)&arow[0]  = v0;
        *(intx4*)&arow[4]  = v1;
        *(intx4*)&arow[8]  = z4;
        *(intx4*)&arow[12] = z4;
        *(float*)&arow[16] = temp_t;
    }

    // ---- layer 0: C-init = bias + temp*W[5][n] (fp32), MFMA, gate, paired b32 write ----
    #pragma unroll
    for (int mt = 0; mt < 4; ++mt) {
        const short8 Af = *(const short8*)&sm.A[w][mt * 16 + n][quad * 8];
        const int rb = mt * 16 + quad * 4;
        floatx4 tv;
        #pragma unroll
        for (int r = 0; r < 4; ++r)
            tv[r] = *(const float*)&sm.A[w][rb + r][32];   // broadcast reads
        floatx4 g0, g1;
        {
            floatx4 Ca, Cb;
            #pragma unroll
            for (int r = 0; r < 4; ++r) {
                Ca[r] = fmaf(tv[r], w5a[0], bA0[0]);
                Cb[r] = fmaf(tv[r], w5b[0], bB0[0]);
            }
            Ca = __builtin_amdgcn_mfma_f32_16x16x32_bf16(Af, Ba0f[0], Ca, 0, 0, 0);
            Cb = __builtin_amdgcn_mfma_f32_16x16x32_bf16(Af, Bb0f[0], Cb, 0, 0, 0);
            #pragma unroll
            for (int r = 0; r < 4; ++r) g0[r] = gate2(Ca[r], Cb[r]);
        }
        {
            floatx4 Ca, Cb;
            #pragma unroll
            for (int r = 0; r < 4; ++r) {
                Ca[r] = fmaf(tv[r], w5a[1], bA0[1]);
                Cb[r] = fmaf(tv[r], w5b[1], bB0[1]);
            }
            Ca = __builtin_amdgcn_mfma_f32_16x16x32_bf16(Af, Ba0f[1], Ca, 0, 0, 0);
            Cb = __builtin_amdgcn_mfma_f32_16x16x32_bf16(Af, Bb0f[1], Cb, 0, 0, 0);
            #pragma unroll
            for (int r = 0; r < 4; ++r) g1[r] = gate2(Ca[r], Cb[r]);
        }
        #pragma unroll
        for (int r = 0; r < 4; ++r)
            ((int*)&sm.A[w][rb + r][0])[n] = cvtpk(g0[r], g1[r]);   // phys cols 2n,2n+1
    }

    // ---- layer 1 (B k-permuted to match the interleaved storage) ----
    #pragma unroll
    for (int mt = 0; mt < 4; ++mt) {
        const short8 Af = *(const short8*)&sm.A[w][mt * 16 + n][quad * 8];
        const int rb = mt * 16 + quad * 4;
        floatx4 g0, g1;
        {
            floatx4 Ca = { bA1[0], bA1[0], bA1[0], bA1[0] };
            floatx4 Cb = { bB1[0], bB1[0], bB1[0], bB1[0] };
            Ca = __builtin_amdgcn_mfma_f32_16x16x32_bf16(Af, Ba1f[0], Ca, 0, 0, 0);
            Cb = __builtin_amdgcn_mfma_f32_16x16x32_bf16(Af, Bb1f[0], Cb, 0, 0, 0);
            #pragma unroll
            for (int r = 0; r < 4; ++r) g0[r] = gate2(Ca[r], Cb[r]);
        }
        {
            floatx4 Ca = { bA1[1], bA1[1], bA1[1], bA1[1] };
            floatx4 Cb = { bB1[1], bB1[1], bB1[1], bB1[1] };
            Ca = __builtin_amdgcn_mfma_f32_16x16x32_bf16(Af, Ba1f[1], Ca, 0, 0, 0);
            Cb = __builtin_amdgcn_mfma_f32_16x16x32_bf16(Af, Bb1f[1], Cb, 0, 0, 0);
            #pragma unroll
            for (int r = 0; r < 4; ++r) g1[r] = gate2(Ca[r], Cb[r]);
        }
        #pragma unroll
        for (int r = 0; r < 4; ++r)
            ((int*)&sm.A[w][rb + r][0])[n] = cvtpk(g0[r], g1[r]);
    }

    // ---- heads: prefetch all A-frags, then MFMA + fp32 transpose via LDS ----
    // All traffic below is within this wave's private A zone; DS ops are in-order
    // per wave, so a compiler-only fence replaces a block barrier here.
    short8 Ah[4];
    #pragma unroll
    for (int mt = 0; mt < 4; ++mt)
        Ah[mt] = *(const short8*)&sm.A[w][mt * 16 + n][quad * 8];
    asm volatile("" ::: "memory");   // pin short-typed reads above before float stores below

    // fp32 transpose buffer: stride 13 dwords (odd -> conflict-free b128 reads).
    float* hc = (float*)&sm.A[w][0][0];
    #pragma unroll
    for (int mt = 0; mt < 4; ++mt) {
        floatx4 C = { hbias, hbias, hbias, hbias };
        C = __builtin_amdgcn_mfma_f32_16x16x32_bf16(Ah[mt], Bhf, C, 0, 0, 0);
        if (n < 8) {
            #pragma unroll
            for (int r = 0; r < 4; ++r)
                hc[(mt * 16 + quad * 4 + r) * 13 + n] = C[r];
        }
    }
    asm volatile("" ::: "memory");   // stores above complete (in-order DS) before reads below

    const floatx4 h0v = *(const floatx4*)&hc[lane * 13];      // pa, pb, pg, pc0
    const floatx4 h1v = *(const floatx4*)&hc[lane * 13 + 4];  // pc1..pc4

    // ---- per-token epilogue ----
    const float alpha = __expf(h0v[0]);
    const float beta  = __expf(h0v[1]);
    const float gamma = __expf(h0v[2]);
    const float z     = 1.0f - __expf(-(alpha * fabsf(df0) + beta * df1 + gamma * fabsf(df2)));
    const float omz   = 1.0f - z;

    const float c0 = fast_tanh(h0v[3]), c1 = fast_tanh(h1v[0]), c2 = fast_tanh(h1v[1]),
                c3 = fast_tanh(h1v[2]), c4 = fast_tanh(h1v[3]);

    const float hn0 = omz * hp0 + z * c0;
    const float hn1 = omz * hp1 + z * c1;
    const float hn2 = omz * hp2 + z * c2;
    const float hn3 = omz * hp3 + z * c3;
    const float hn4 = omz * hp4 + z * c4;

    float* out_h = out + (size_t)t * 5;
    out_h[0] = hn0; out_h[1] = hn1; out_h[2] = hn2; out_h[3] = hn3; out_h[4] = hn4;
    out[(size_t)N_TOK * 5 + t] =
        hn0 * W_out[0] + hn1 * W_out[1] + hn2 * W_out[2] + hn3 * W_out[3] + hn4 * W_out[4];
}

extern "C" void kernel_launch(void* const* d_in, const int* in_sizes, int n_in,
                              void* d_out, int out_size, void* d_ws, size_t ws_size,
                              hipStream_t stream) {
    const float* h_prev  = (const float*)d_in[0];
    const float* dx      = (const float*)d_in[1];
    const float* Wa0     = (const float*)d_in[2];
    const float* ba0     = (const float*)d_in[3];
    const float* Wb0     = (const float*)d_in[4];
    const float* bb0     = (const float*)d_in[5];
    const float* Wa1     = (const float*)d_in[6];
    const float* ba1     = (const float*)d_in[7];
    const float* Wb1     = (const float*)d_in[8];
    const float* bb1     = (const float*)d_in[9];
    const float* W_alpha = (const float*)d_in[10];
    const float* b_alpha = (const float*)d_in[11];
    const float* W_beta  = (const float*)d_in[12];
    const float* b_beta  = (const float*)d_in[13];
    const float* W_gamma = (const float*)d_in[14];
    const float* b_gamma = (const float*)d_in[15];
    const float* W_c     = (const float*)d_in[16];
    const float* b_c     = (const float*)d_in[17];
    const float* W_out   = (const float*)d_in[18];
    float* out = (float*)d_out;

    chunksum_kernel<<<N_CHUNK, CHUNK, 0, stream>>>(dx);
    msc_kernel<<<N_CHUNK, CHUNK, 0, stream>>>(
        h_prev, dx,
        Wa0, ba0, Wb0, bb0, Wa1, ba1, Wb1, bb1,
        W_alpha, b_alpha, W_beta, b_beta, W_gamma, b_gamma,
        W_c, b_c, W_out, out);
}